// Round 2
// baseline (154.510 us; speedup 1.0000x reference)
//
#include <hip/hip_runtime.h>

#define BB    2048
#define TT    1024
#define TAILN 8
#define NSEQ  (BB * TAILN)          // 16384 independent sequences
#define NELEM (BB * TT * TAILN)     // 16,777,216 elements per array

#define CHUNK  256                  // T-chunk per thread
#define WARM   128                  // warm-up steps; carry decays by 0.9405^128 ~ 3.9e-4
#define NCHUNK (TT / CHUNK)         // 4 chunks -> 65536 threads = 4 waves/CU

// ---------------------------------------------------------------------------
// terminated-dtype detection (bool u8 / int32 / float32), single block.
//   float32 data -> words 0 or 0x3F800000      (evidence bit 2)
//   bool bytes   -> words with bytes in {0,1}; any word>1 is bool evidence
//   int32 data   -> words only {0,1}           (no evidence -> mode 0)
// ---------------------------------------------------------------------------
static __global__ __launch_bounds__(1024)
void detect_kernel(const unsigned int* __restrict__ term, int* __restrict__ flag) {
    __shared__ int sflag;
    if (threadIdx.x == 0) sflag = 0;
    __syncthreads();
    int ev = 0;
    for (unsigned i = threadIdx.x; i < 65536u; i += 1024u) {  // 256 KB scan
        unsigned w = term[i];
        if (w == 0x3F800000u) ev |= 2;        // float 1.0f
        else if (w > 1u)      ev |= 1;        // packed bool bytes
    }
    if (ev) atomicOr(&sflag, ev);
    __syncthreads();
    if (threadIdx.x == 0) *flag = sflag;
}

template <int MODE>
__device__ __forceinline__ float nd_load(const void* __restrict__ termv, int idx) {
    if (MODE == 1) return ((const unsigned char*)termv)[idx] ? 0.0f : 1.0f;
    if (MODE == 2) return 1.0f - ((const float*)termv)[idx];
    return ((const int*)termv)[idx] ? 0.0f : 1.0f;
}

// ---------------------------------------------------------------------------
// main kernel: one thread per (sequence, T-chunk). Warm-up scan (no stores)
// approximates the carry from the right; error <= 0.9405^WARM * max|gae|.
// ---------------------------------------------------------------------------
template <int MODE>
__device__ __forceinline__ void gae_chunk(int sid, int c,
    const float* __restrict__ reward, const void* __restrict__ term,
    const float* __restrict__ value,  const float* __restrict__ nextv,
    float* __restrict__ adv, float* __restrict__ ret)
{
    const float g  = 0.99f;
    const float gl = 0.99f * 0.95f;
    const int base   = (sid >> 3) * (TT * TAILN) + (sid & 7);
    const int lo     = c * CHUNK;
    const int mainhi = lo + CHUNK;                                   // exclusive
    const int warmhi = (c == NCHUNK - 1) ? mainhi : mainhi + WARM;   // exclusive

    float gae = 0.0f;
    #pragma unroll 8
    for (int t = warmhi - 1; t >= mainhi; --t) {      // warm-up, no stores
        const int idx = base + t * TAILN;
        const float nd = nd_load<MODE>(term, idx);
        const float d  = fmaf(g * nd, nextv[idx], reward[idx]) - value[idx];
        gae = fmaf(gl * nd, gae, d);
    }
    #pragma unroll 8
    for (int t = mainhi - 1; t >= lo; --t) {          // main chunk, stores
        const int idx = base + t * TAILN;
        const float nd = nd_load<MODE>(term, idx);
        const float v  = value[idx];
        const float d  = fmaf(g * nd, nextv[idx], reward[idx]) - v;
        gae = fmaf(gl * nd, gae, d);
        __builtin_nontemporal_store(gae,     &adv[idx]);
        __builtin_nontemporal_store(gae + v, &ret[idx]);
    }
}

__global__ __launch_bounds__(256)
void gae_kernel(const float* __restrict__ reward, const void* __restrict__ term,
                const float* __restrict__ value,  const float* __restrict__ nextv,
                float* __restrict__ adv, float* __restrict__ ret,
                const int* __restrict__ flag)
{
    const int tid = blockIdx.x * blockDim.x + threadIdx.x;
    const int sid = tid & (NSEQ - 1);    // contiguous within a wave -> coalesced
    const int c   = tid >> 14;           // NSEQ = 2^14; wave-uniform chunk id
    const int f = *flag;                 // wave-uniform
    if (f & 1)      gae_chunk<1>(sid, c, reward, term, value, nextv, adv, ret);
    else if (f & 2) gae_chunk<2>(sid, c, reward, term, value, nextv, adv, ret);
    else            gae_chunk<0>(sid, c, reward, term, value, nextv, adv, ret);
}

extern "C" void kernel_launch(void* const* d_in, const int* in_sizes, int n_in,
                              void* d_out, int out_size, void* d_ws, size_t ws_size,
                              hipStream_t stream) {
    const float* reward = (const float*)d_in[0];
    const void*  term   = d_in[1];
    const float* value  = (const float*)d_in[2];
    const float* nextv  = (const float*)d_in[3];
    float* adv  = (float*)d_out;            // advantages: first NELEM floats
    float* ret  = adv + NELEM;              // returns:    next NELEM floats
    int*   flag = (int*)d_ws;

    hipLaunchKernelGGL(detect_kernel, dim3(1), dim3(1024), 0, stream,
                       (const unsigned int*)term, flag);
    hipLaunchKernelGGL(gae_kernel, dim3((NCHUNK * NSEQ) / 256), dim3(256), 0, stream,
                       reward, term, value, nextv, adv, ret, flag);
}

// Round 3
// 116.617 us; speedup vs baseline: 1.3249x; 1.3249x over previous
//
#include <hip/hip_runtime.h>

#define BB    2048
#define TT    1024
#define TAILN 8
#define NELEM (BB * TT * TAILN)

#define CHUNK   256
#define WARM    128                 // carry decays by 0.9405^128 ~ 3.9e-4
#define NCHUNK  (TT / CHUNK)        // 4
#define BGB     16                  // b's per block
#define NBG     (BB / BGB)          // 128 b-groups
#define TTILE   8                   // t's per staged tile
#define THREADS 128                 // BGB*TAILN sequences, 2 waves
#define DEPTH   3                   // LDS ring depth

#define ASZ     (BGB * TTILE * TAILN * 4)   // 4096 B per f32 array per tile
#define LDS_MAX (3 * 4 * 4096 + 2 * 4096)   // 3 bufs * 4 arrays + 2 out = 57344 B

// ---------------------------------------------------------------------------
// terminated-dtype detection (bool u8 / int32 / float32), single block.
// ---------------------------------------------------------------------------
static __global__ __launch_bounds__(1024)
void detect_kernel(const unsigned int* __restrict__ term, int* __restrict__ flag) {
    __shared__ int sflag;
    if (threadIdx.x == 0) sflag = 0;
    __syncthreads();
    int ev = 0;
    for (unsigned i = threadIdx.x; i < 65536u; i += 1024u) {
        unsigned w = term[i];
        if (w == 0x3F800000u) ev |= 2;        // float 1.0f
        else if (w > 1u)      ev |= 1;        // packed bool bytes
    }
    if (ev) atomicOr(&sflag, ev);
    __syncthreads();
    if (threadIdx.x == 0) *flag = sflag;
}

__device__ __forceinline__ void gload16(const void* g, void* l) {
    __builtin_amdgcn_global_load_lds(
        (const __attribute__((address_space(1))) void*)g,
        (__attribute__((address_space(3))) void*)l, 16, 0, 0);
}

#define WAITV(N) asm volatile("s_waitcnt vmcnt(" #N ") lgkmcnt(0)" ::: "memory")

// ---------------------------------------------------------------------------
// staged GAE: block owns BGB b's and one T-chunk (+WARM).  Tiles of TTILE t's
// ride a DEPTH-deep LDS ring fed by global_load_lds (counted vmcnt, never 0
// in steady state).  LDS layout per f32 array: [b][(t*8+tail) ^ ((b&3)<<3)]
// (pre-swizzled global source, rule 21) -> compute reads are 2-way = free.
// ---------------------------------------------------------------------------
template <int MODE>
__device__ __forceinline__ void gae_run(
    const float* __restrict__ r, const void* __restrict__ term,
    const float* __restrict__ v, const float* __restrict__ nv,
    float* __restrict__ adv, float* __restrict__ ret,
    unsigned char* smem, int bg, int c, int tid)
{
    constexpr int TERMB = (MODE == 1) ? (BGB * TTILE * TAILN) : ASZ; // 1KB or 4KB
    constexpr int TS    = 3 * ASZ + TERMB;        // tile stride: 13312 / 16384
    constexpr int OUTO  = DEPTH * TS;             // out staging base
    constexpr int NSLOT = TS / 1024;              // 13 / 16  (1KB stage slots)
    const int lane = tid & 63;
    const int w    = tid >> 6;                    // wave id (0,1)
    const int NT   = (c == NCHUNK - 1) ? (CHUNK / TTILE)
                                       : ((CHUNK + WARM) / TTILE);   // 32 / 48
    const int t0c  = c * CHUNK;
    const size_t brow = (size_t)bg * BGB;

    auto stage = [&](int i) {
        const int t0   = t0c + i * TTILE;
        const int bufo = (i % DEPTH) * TS;
        for (int s = w; s < NSLOT; s += 2) {
            if (MODE == 1 && s == 12) {           // term as bytes: one 1KB slot
                const int b = lane >> 2;
                const int o = (lane & 3) * 16;
                const unsigned char* g = (const unsigned char*)term
                    + (brow + b) * (size_t)(TT * TAILN) + (size_t)t0 * TAILN + o;
                gload16(g, smem + bufo + 3 * ASZ);
            } else {                              // f32 arrays (+ term words)
                const int a = s >> 2;             // 0 r, 1 v, 2 nv, 3 term
                const int k = s & 3;
                const int b = k * 4 + (lane >> 4);
                const int o = ((lane & 15) * 16) ^ ((b & 3) << 5);  // pre-swizzle
                const char* gp = (a == 0) ? (const char*)r
                               : (a == 1) ? (const char*)v
                               : (a == 2) ? (const char*)nv : (const char*)term;
                const char* g = gp
                    + ((brow + b) * (size_t)(TT * TAILN) + (size_t)t0 * TAILN) * 4 + o;
                gload16(g, smem + bufo + a * ASZ + k * 1024);
            }
        }
    };

    const int b_l  = tid >> 3;                    // 0..15
    const int tail = tid & 7;
    const int swb  = (b_l & 3) << 5;              // byte XOR for swizzled reads
    float gae = 0.0f;

    stage(NT - 1);
    stage(NT - 2);

    for (int i = NT - 1; i >= 0; --i) {
        if (i >= 2) stage(i - 2);
        // wait for own share of stage(i): <= 2 tiles of own loads outstanding
        if (i >= 2) {
            if (MODE == 1) { if (w == 0) WAITV(14); else WAITV(12); }
            else           { WAITV(16); }
        } else             { WAITV(0); }
        __builtin_amdgcn_s_barrier();             // tile i resident (all waves)

        const int bufo = (i % DEPTH) * TS;
        const int t0   = t0c + i * TTILE;
        const bool st  = (i < CHUNK / TTILE);     // main-chunk tile -> store
        #pragma unroll
        for (int tl = TTILE - 1; tl >= 0; --tl) {
            const int wo = ((tl * TAILN + tail) * 4) ^ swb;
            const float rr = *(const float*)(smem + bufo + 0 * ASZ + b_l * 256 + wo);
            const float vv = *(const float*)(smem + bufo + 1 * ASZ + b_l * 256 + wo);
            const float nn = *(const float*)(smem + bufo + 2 * ASZ + b_l * 256 + wo);
            float nd;
            if (MODE == 1)
                nd = smem[bufo + 3 * ASZ + b_l * 64 + tl * TAILN + tail] ? 0.0f : 1.0f;
            else if (MODE == 2)
                nd = 1.0f - *(const float*)(smem + bufo + 3 * ASZ + b_l * 256 + wo);
            else
                nd = (*(const int*)(smem + bufo + 3 * ASZ + b_l * 256 + wo)) ? 0.0f : 1.0f;
            const float d = fmaf(0.99f * nd, nn, rr) - vv;
            gae = fmaf(0.9405f * nd, gae, d);
            if (st) {
                *(float*)(smem + OUTO + 0 * ASZ + b_l * 256 + wo) = gae;
                *(float*)(smem + OUTO + 1 * ASZ + b_l * 256 + wo) = gae + vv;
            }
        }
        asm volatile("s_waitcnt lgkmcnt(0)" ::: "memory");
        __builtin_amdgcn_s_barrier();             // outs written; buf i free next iter

        if (st) {                                 // coalesced store of out tiles
            for (int s = w; s < 8; s += 2) {
                const int a = s >> 2;             // 0 adv, 1 ret
                const int k = s & 3;
                const int b = k * 4 + (lane >> 4);
                const int o = ((lane & 15) * 16) ^ ((b & 3) << 5);
                const float4 val =
                    *(const float4*)(smem + OUTO + a * ASZ + k * 1024 + lane * 16);
                float* gp = (a == 0) ? adv : ret;
                *(float4*)((char*)gp
                    + ((brow + b) * (size_t)(TT * TAILN) + (size_t)t0 * TAILN) * 4 + o) = val;
            }
        }
    }
}

__global__ __launch_bounds__(THREADS)
void gae_kernel(const float* __restrict__ r, const void* __restrict__ term,
                const float* __restrict__ v, const float* __restrict__ nv,
                float* __restrict__ adv, float* __restrict__ ret,
                const int* __restrict__ flag)
{
    __shared__ __align__(16) unsigned char smem[LDS_MAX];
    const int bg  = blockIdx.x >> 2;              // b-group
    const int c   = blockIdx.x & 3;               // T-chunk
    const int tid = threadIdx.x;
    const int f = *flag;
    if (f & 1)      gae_run<1>(r, term, v, nv, adv, ret, smem, bg, c, tid);
    else if (f & 2) gae_run<2>(r, term, v, nv, adv, ret, smem, bg, c, tid);
    else            gae_run<0>(r, term, v, nv, adv, ret, smem, bg, c, tid);
}

extern "C" void kernel_launch(void* const* d_in, const int* in_sizes, int n_in,
                              void* d_out, int out_size, void* d_ws, size_t ws_size,
                              hipStream_t stream) {
    const float* reward = (const float*)d_in[0];
    const void*  term   = d_in[1];
    const float* value  = (const float*)d_in[2];
    const float* nextv  = (const float*)d_in[3];
    float* adv  = (float*)d_out;
    float* ret  = adv + NELEM;
    int*   flag = (int*)d_ws;

    hipLaunchKernelGGL(detect_kernel, dim3(1), dim3(1024), 0, stream,
                       (const unsigned int*)term, flag);
    hipLaunchKernelGGL(gae_kernel, dim3(NBG * NCHUNK), dim3(THREADS), 0, stream,
                       reward, term, value, nextv, adv, ret, flag);
}

// Round 4
// 115.587 us; speedup vs baseline: 1.3367x; 1.0089x over previous
//
#include <hip/hip_runtime.h>

#define BB    2048
#define TT    1024
#define TAILN 8
#define NELEM (BB * TT * TAILN)
#define WARM  128                   // carry decays by 0.9405^128 ~ 3.9e-4

// ---------------------------------------------------------------------------
// terminated-dtype detection (bool u8 / int32 / float32), single block.
//   float32 data -> words 0 or 0x3F800000      (evidence bit 2)
//   bool bytes   -> words with bytes in {0,1}; any word>1 is bool evidence
//   int32 data   -> words only {0,1}           (no evidence -> mode 0)
// ---------------------------------------------------------------------------
static __global__ __launch_bounds__(1024)
void detect_kernel(const unsigned int* __restrict__ term, int* __restrict__ flag) {
    __shared__ int sflag;
    if (threadIdx.x == 0) sflag = 0;
    __syncthreads();
    int ev = 0;
    for (unsigned i = threadIdx.x; i < 65536u; i += 1024u) {
        unsigned w = term[i];
        if (w == 0x3F800000u) ev |= 2;        // float 1.0f
        else if (w > 1u)      ev |= 1;        // packed bool bytes
    }
    if (ev) atomicOr(&sflag, ev);
    __syncthreads();
    if (threadIdx.x == 0) *flag = sflag;
}

template <int MODE>
__device__ __forceinline__ float nd_load(const void* __restrict__ termv, int idx) {
    if (MODE == 1) return ((const unsigned char*)termv)[idx] ? 0.0f : 1.0f;
    if (MODE == 2) return 1.0f - ((const float*)termv)[idx];
    return ((const int*)termv)[idx] ? 0.0f : 1.0f;
}

// ---------------------------------------------------------------------------
// Phase-staggered chunked scan.
//   wave -> (b-group g = blockIdx, chunk c = threadIdx>>6), sigma = (g&31)*8.
//   Chunk windows per sequence:  [0,256-s) [256-s,512-s) [512-s,768-s) [768-s,1024)
//   c<3 warm up WARM extra steps (gae=0 seed, decayed to <4e-4); c=3 is exact.
//   At any instant the machine covers 4 chunk phases x 32 sigma phases
//   = 256B-granular coverage of the full 32KiB b-row period -> all DRAM
//   channels active.  Per-block work is constant (1408 t's) by construction.
// ---------------------------------------------------------------------------
template <int MODE>
__device__ __forceinline__ void gae_chunk(int b, int tail, int store_lo,
    int store_hi, int warm_hi,
    const float* __restrict__ reward, const void* __restrict__ term,
    const float* __restrict__ value,  const float* __restrict__ nextv,
    float* __restrict__ adv, float* __restrict__ ret)
{
    const float g  = 0.99f;
    const float gl = 0.99f * 0.95f;
    const int base = b * (TT * TAILN) + tail;

    float gae = 0.0f;
    #pragma unroll 8
    for (int t = warm_hi - 1; t >= store_hi; --t) {   // warm-up, no stores
        const int idx = base + t * TAILN;
        const float nd = nd_load<MODE>(term, idx);
        const float d  = fmaf(g * nd, nextv[idx], reward[idx]) - value[idx];
        gae = fmaf(gl * nd, gae, d);
    }
    #pragma unroll 8
    for (int t = store_hi - 1; t >= store_lo; --t) {  // stored range
        const int idx = base + t * TAILN;
        const float nd = nd_load<MODE>(term, idx);
        const float v  = value[idx];
        const float d  = fmaf(g * nd, nextv[idx], reward[idx]) - v;
        gae = fmaf(gl * nd, gae, d);
        adv[idx] = gae;
        ret[idx] = gae + v;
    }
}

__global__ __launch_bounds__(256)
void gae_kernel(const float* __restrict__ reward, const void* __restrict__ term,
                const float* __restrict__ value,  const float* __restrict__ nextv,
                float* __restrict__ adv, float* __restrict__ ret,
                const int* __restrict__ flag)
{
    const int grp   = blockIdx.x;            // b-group: 8 consecutive b's
    const int c     = threadIdx.x >> 6;      // chunk id, uniform per wave
    const int lane  = threadIdx.x & 63;
    const int b     = grp * 8 + (lane >> 3);
    const int tail  = lane & 7;
    const int sigma = (grp & 31) * 8;        // phase stagger, 0..248 t's

    int store_lo = c * 256 - sigma; if (store_lo < 0) store_lo = 0;
    const int store_hi = (c == 3) ? TT : (c + 1) * 256 - sigma;
    const int warm_hi  = (c == 3) ? TT : store_hi + WARM;

    const int f = *flag;                     // wave-uniform
    if (f & 1)      gae_chunk<1>(b, tail, store_lo, store_hi, warm_hi,
                                 reward, term, value, nextv, adv, ret);
    else if (f & 2) gae_chunk<2>(b, tail, store_lo, store_hi, warm_hi,
                                 reward, term, value, nextv, adv, ret);
    else            gae_chunk<0>(b, tail, store_lo, store_hi, warm_hi,
                                 reward, term, value, nextv, adv, ret);
}

extern "C" void kernel_launch(void* const* d_in, const int* in_sizes, int n_in,
                              void* d_out, int out_size, void* d_ws, size_t ws_size,
                              hipStream_t stream) {
    const float* reward = (const float*)d_in[0];
    const void*  term   = d_in[1];
    const float* value  = (const float*)d_in[2];
    const float* nextv  = (const float*)d_in[3];
    float* adv  = (float*)d_out;            // advantages: first NELEM floats
    float* ret  = adv + NELEM;              // returns:    next NELEM floats
    int*   flag = (int*)d_ws;

    hipLaunchKernelGGL(detect_kernel, dim3(1), dim3(1024), 0, stream,
                       (const unsigned int*)term, flag);
    // 256 blocks x 256 threads: block = one b-group, its 4 waves = 4 chunks.
    hipLaunchKernelGGL(gae_kernel, dim3(BB / 8), dim3(256), 0, stream,
                       reward, term, value, nextv, adv, ret, flag);
}